// Round 16
// baseline (159.398 us; speedup 1.0000x reference)
//
#include <hip/hip_runtime.h>
#include <hip/hip_bf16.h>
#include <cstdint>
#include <cstddef>

// LSTMCell: gates = [input|hx] @ [Wih|Whh]^T + b_ih + b_hh  (4096 x 4096 x K=2048)
// Round 16: single-product f16 GEMM (absmax 0.051 verified R8-R15). R8 skeleton
// (256x256 tile, 8 waves, BK=32, ring-3 LDS, counted vmcnt) + m201-style ONE-PHASE-
// AHEAD register pipeline: each phase's ds_reads were issued a full phase earlier,
// so lgkm waits are ~free and fresh reads drain UNDER the MFMA cluster. One barrier
// per K-step. WAR-safety: slot (t-1)%3 last read before barrier(t-1); re-staged
// after it. vmcnt(4) before the barrier -> all waves' stage(t+1) landed.

#define B_ROWS 4096
#define HDIM   1024
#define KDIM   2048
#define BM     256
#define BK     32
#define T_STEPS (KDIM / BK)   // 64

typedef unsigned short u16;
using f32x4  = __attribute__((ext_vector_type(4))) float;
using short8 = __attribute__((ext_vector_type(8))) short;
using half8  = __attribute__((ext_vector_type(8))) _Float16;

__device__ __forceinline__ u16 f2h_bits(float f) {
    _Float16 h = (_Float16)f;                    // v_cvt_f16_f32, RTN
    return __builtin_bit_cast(u16, h);
}

// ---------------- pack: f32 -> f16, concat K-dim (same as R8) ----------------
__global__ void pack_kernel(const float* __restrict__ input, const float* __restrict__ hx,
                            const float* __restrict__ wih, const float* __restrict__ whh,
                            u16* __restrict__ Af, u16* __restrict__ Wf)
{
    const int PER = (B_ROWS * KDIM) / 4;  // float4 groups per matrix
    int stride = gridDim.x * blockDim.x;
    for (int i = blockIdx.x * blockDim.x + threadIdx.x; i < 2 * PER; i += stride) {
        int isW = (i >= PER) ? 1 : 0;
        int e = i - isW * PER;
        int row = e >> 9;            // 512 float4-groups per row of 2048
        int k = (e & 511) << 2;
        const float* s0 = isW ? wih : input;
        const float* s1 = isW ? whh : hx;
        const float* src = (k < 1024) ? (s0 + (size_t)row * 1024 + k)
                                      : (s1 + (size_t)row * 1024 + (k - 1024));
        float4 v = *(const float4*)src;
        size_t doff = (size_t)row * KDIM + k;
        u16* dst = (isW ? Wf : Af) + doff;
        *(ushort4*)dst = make_ushort4(f2h_bits(v.x), f2h_bits(v.y),
                                      f2h_bits(v.z), f2h_bits(v.w));
    }
}

// ---------------- fused GEMM + LSTM epilogue ----------------
__device__ __forceinline__ void gload16(const void* g, void* l) {
    __builtin_amdgcn_global_load_lds((const __attribute__((address_space(1))) void*)g,
                                     (__attribute__((address_space(3))) void*)l, 16, 0, 0);
}
__device__ __forceinline__ float sigmf(float x) { return 1.0f / (1.0f + __expf(-x)); }
__device__ __forceinline__ float tanhfast(float x) { return 1.0f - 2.0f / (1.0f + __expf(2.0f * x)); }

__launch_bounds__(512, 1)
__global__ void lstm_fused(const u16* __restrict__ Afp, const u16* __restrict__ Wfp,
                           const float* __restrict__ cx, const float* __restrict__ eps_c,
                           const float* __restrict__ eps_h,
                           const float* __restrict__ bias_ih, const float* __restrict__ bias_hh,
                           const float* __restrict__ noise_q, const float* __restrict__ noise_e,
                           float* __restrict__ out)
{
    // k-chunk-panel layout [sb(3)][kc(4)][row(256)][8] u16 — linear for global_load_lds,
    // conflict-free ds_read_b128 (0 conflicts measured R1-R15). 96 KB total.
    __shared__ __align__(16) u16 lA[3][4][256][8];
    __shared__ __align__(16) u16 lW[3][4][256][8];

    int bid = blockIdx.x;
    // XCD-bijective swizzle: XCD x gets w in [32x,32x+32) -> 2 hq values
    // (W working set 2 MB, L2-resident) x all 16 A panels.
    int w = (bid & 7) * 32 + (bid >> 3);
    int mi = w & 15;          // 16 M-chunks of 256 rows
    int hq = w >> 4;          // 16 h-chunks of 64 cols (x4 gates = 256 gate-cols)
    int bm0 = mi * BM;
    int h0 = hq * 64;

    int tid  = threadIdx.x;
    int lane = tid & 63;
    int wid  = tid >> 6;      // 0..7
    int wm   = wid >> 2;      // M half (128 rows)
    int wn   = wid & 3;       // h quarter (16 cols x 4 gates = 64 gate-cols)

    // ---- staging mapping: thread -> (row = tid&255, kc base = tid>>8), 2 loads ----
    int rSt = tid & 255;
    int kS  = tid >> 8;       // 0/1
    const u16* Asrc = Afp + (size_t)(bm0 + rSt) * KDIM;
    // LDS W row n <-> global gate row: gate = n>>6, h = h0 + (n&63)
    int wgrow = (rSt >> 6) * 1024 + h0 + (rSt & 63);
    const u16* Wsrc = Wfp + (size_t)wgrow * KDIM;

#define STG_A(sb, t_) do { \
        gload16(Asrc + (t_) * 32 + kS * 8,       &lA[sb][kS][rSt][0]);     \
        gload16(Asrc + (t_) * 32 + (kS + 2) * 8, &lA[sb][kS + 2][rSt][0]); } while (0)
#define STG_W(sb, t_) do { \
        gload16(Wsrc + (t_) * 32 + kS * 8,       &lW[sb][kS][rSt][0]);     \
        gload16(Wsrc + (t_) * 32 + (kS + 2) * 8, &lW[sb][kS + 2][rSt][0]); } while (0)

    // ---- fragment read indices ----
    int fk = lane >> 4, fr = lane & 15;

    f32x4 acc[8][4];   // [m-frag][gate]
#pragma unroll
    for (int m = 0; m < 8; ++m)
#pragma unroll
        for (int g = 0; g < 4; ++g)
            acc[m][g] = (f32x4){0.f, 0.f, 0.f, 0.f};

#define LD8(p) __builtin_bit_cast(half8, *(const short8*)(p))
#define SB0()  __builtin_amdgcn_sched_barrier(0)

#define MFMA16(mb, A0, A1, A2, A3, WF) do { \
        _Pragma("unroll") \
        for (int g = 0; g < 4; ++g) { \
            acc[(mb)][g]     = __builtin_amdgcn_mfma_f32_16x16x32_f16(A0, WF[g], acc[(mb)][g], 0, 0, 0); \
            acc[(mb) + 1][g] = __builtin_amdgcn_mfma_f32_16x16x32_f16(A1, WF[g], acc[(mb) + 1][g], 0, 0, 0); \
        } \
        _Pragma("unroll") \
        for (int g = 0; g < 4; ++g) { \
            acc[(mb) + 2][g] = __builtin_amdgcn_mfma_f32_16x16x32_f16(A2, WF[g], acc[(mb) + 2][g], 0, 0, 0); \
            acc[(mb) + 3][g] = __builtin_amdgcn_mfma_f32_16x16x32_f16(A3, WF[g], acc[(mb) + 3][g], 0, 0, 0); \
        } \
    } while (0)

    half8 wfP[4], wfQ[4];
    half8 a0, a1, a2, a3, a4, a5, a6, a7;

    // ---- prologue: stage slots 0,1; drain own slot-0 loads; barrier => all landed;
    //      read step-0 operands (Wp, a0-3) — compiler lgkm-waits before first MFMA.
    STG_A(0, 0); STG_W(0, 0);
    STG_A(1, 1); STG_W(1, 1);
    asm volatile("s_waitcnt vmcnt(4)");
    __builtin_amdgcn_s_barrier();
    {
        const u16* pA0 = &lA[0][fk][wm * 128 + fr][0];
        const u16* pW0 = &lW[0][fk][wn * 16 + fr][0];
        wfP[0] = LD8(pW0);        wfP[1] = LD8(pW0 + 512);
        wfP[2] = LD8(pW0 + 1024); wfP[3] = LD8(pW0 + 1536);
        a0 = LD8(pA0);           a1 = LD8(pA0 + 128);
        a2 = LD8(pA0 + 256);     a3 = LD8(pA0 + 384);
    }

    // One K-step: WU = this step's W regs; WN receives next step's.
#define STEP(t_, WU, WN) do { \
        const int scur = (t_) % 3; \
        const int snxt = ((t_) + 1) % 3; \
        const int spre = ((t_) + 2) % 3; \
        const bool pre2 = (t_) < T_STEPS - 2; \
        const bool preN = (t_) < T_STEPS - 1; \
        /* ---- Phase A: stage(t+2); read a4-7(slot t); counted vmcnt; BARRIER ---- */ \
        if (pre2) { STG_A(spre, (t_) + 2); STG_W(spre, (t_) + 2); } \
        { const u16* pAc = &lA[scur][fk][wm * 128 + fr][0]; \
          a4 = LD8(pAc + 512); a5 = LD8(pAc + 640); \
          a6 = LD8(pAc + 768); a7 = LD8(pAc + 896); } \
        SB0(); \
        if (pre2) asm volatile("s_waitcnt vmcnt(4)"); \
        else      asm volatile("s_waitcnt vmcnt(0)"); \
        __builtin_amdgcn_s_barrier(); \
        SB0(); \
        __builtin_amdgcn_s_setprio(1); \
        MFMA16(0, a0, a1, a2, a3, WU);   /* operands read one phase ago: lgkm free */ \
        __builtin_amdgcn_s_setprio(0); \
        SB0(); \
        /* ---- Phase B: read next step's W + a0-3 (slot t+1, valid post-barrier) ---- */ \
        if (preN) { \
            const u16* pAn = &lA[snxt][fk][wm * 128 + fr][0]; \
            const u16* pWn = &lW[snxt][fk][wn * 16 + fr][0]; \
            WN[0] = LD8(pWn);        WN[1] = LD8(pWn + 512); \
            WN[2] = LD8(pWn + 1024); WN[3] = LD8(pWn + 1536); \
            a0 = LD8(pAn);           a1 = LD8(pAn + 128); \
            a2 = LD8(pAn + 256);     a3 = LD8(pAn + 384); \
        } \
        SB0(); \
        __builtin_amdgcn_s_setprio(1); \
        MFMA16(4, a4, a5, a6, a7, WU);   /* a4-7 read last phase; new reads drain under */ \
        __builtin_amdgcn_s_setprio(0); \
        SB0(); \
    } while (0)

#pragma unroll 1
    for (int tt = 0; tt < T_STEPS; tt += 2) {
        STEP(tt,     wfP, wfQ);
        STEP(tt + 1, wfQ, wfP);
    }

    // ---- epilogue: all 4 gates for (r,h) are lane-local ----
    float sq_e = sqrtf(noise_e[0]);
    float sq_q = sqrtf(noise_q[0]);
    int h = h0 + wn * 16 + fr;
    float bsum[4];
#pragma unroll
    for (int g = 0; g < 4; ++g)
        bsum[g] = bias_ih[g * 1024 + h] + bias_hh[g * 1024 + h];
#pragma unroll
    for (int m = 0; m < 8; ++m) {
        int r0 = bm0 + wm * 128 + m * 16 + fk * 4;
#pragma unroll
        for (int j = 0; j < 4; ++j) {
            int r = r0 + j;
            size_t off = (size_t)r * HDIM + h;
            float gi = acc[m][0][j] + bsum[0];
            float gf = acc[m][1][j] + bsum[1];
            float gc = acc[m][2][j] + bsum[2];
            float go = acc[m][3][j] + bsum[3];
            float ig = sigmf(gi), fg = sigmf(gf);
            float cg = tanhfast(gc), og = sigmf(go);
            float cyv = fg * cx[off] + ig * cg + sq_e * eps_c[off];
            float hyv = og * tanhfast(cyv) + sq_q * eps_h[off];
            out[off] = hyv;                                 // hy
            out[(size_t)B_ROWS * HDIM + off] = cyv;         // cy
        }
    }
}

extern "C" void kernel_launch(void* const* d_in, const int* in_sizes, int n_in,
                              void* d_out, int out_size, void* d_ws, size_t ws_size,
                              hipStream_t stream)
{
    const float* input = (const float*)d_in[0];
    const float* hx    = (const float*)d_in[1];
    const float* cx    = (const float*)d_in[2];
    const float* nq    = (const float*)d_in[3];
    const float* ne    = (const float*)d_in[4];
    const float* wih   = (const float*)d_in[5];
    const float* whh   = (const float*)d_in[6];
    const float* bih   = (const float*)d_in[7];
    const float* bhh   = (const float*)d_in[8];
    const float* epsc  = (const float*)d_in[9];
    const float* epsh  = (const float*)d_in[10];
    float* out = (float*)d_out;

    u16* Af = (u16*)d_ws;
    u16* Wf = Af + (size_t)B_ROWS * KDIM;   // 32 MB of ws total

    hipLaunchKernelGGL(pack_kernel, dim3(2048), dim3(256), 0, stream,
                       input, hx, wih, whh, Af, Wf);
    hipLaunchKernelGGL(lstm_fused, dim3(256), dim3(512), 0, stream,
                       Af, Wf, cx, epsc, epsh, bih, bhh, nq, ne, out);
}

// Round 17
// 98.824 us; speedup vs baseline: 1.6129x; 1.6129x over previous
//
#include <hip/hip_runtime.h>
#include <hip/hip_bf16.h>
#include <cstdint>
#include <cstddef>

// LSTMCell: gates = [input|hx] @ [Wih|Whh]^T + b_ih + b_hh  (4096 x 4096 x K=2048)
// Round 17: R13 (best, 101 us) + two local fixes:
//  (1) epilogue batch-load: issue all 96 cx/eps loads into freed operand regs,
//      one pipelined HBM-latency exposure instead of eight;
//  (2) bumped base pointers in the K-loop (imm-offset loads, less 64-bit VALU).
// Structure unchanged: no LDS, no barriers, self-paced waves, reg double-buffer.
//
// A layout: [mi(16)][wm(2)][kt(64)][m(8)][lane(64)][8 u16]
// W layout: [hq(16)][wn(4)][kt(64)][g(4)][lane(64)][8 u16]

#define B_ROWS 4096
#define HDIM   1024
#define KDIM   2048
#define BM     256
#define T_STEPS 64

typedef unsigned short u16;
using f32x4  = __attribute__((ext_vector_type(4))) float;
using short8 = __attribute__((ext_vector_type(8))) short;
using half8  = __attribute__((ext_vector_type(8))) _Float16;

__device__ __forceinline__ u16 f2h_bits(float f) {
    _Float16 h = (_Float16)f;                    // v_cvt_f16_f32, RTN
    return __builtin_bit_cast(u16, h);
}

// ---------------- pack: f32 -> f16 fragment-major (same as R13) ----------------
__global__ void pack_kernel(const float* __restrict__ input, const float* __restrict__ hx,
                            const float* __restrict__ wih, const float* __restrict__ whh,
                            u16* __restrict__ Ap, u16* __restrict__ Wp)
{
    const int NA = 16 * 2 * 64 * 8 * 64;   // 1,048,576 16B-groups
    const int NW = 16 * 4 * 64 * 4 * 64;   // 1,048,576
    int stride = gridDim.x * blockDim.x;
    for (int i = blockIdx.x * blockDim.x + threadIdx.x; i < NA + NW; i += stride) {
        int isW = (i >= NA) ? 1 : 0;
        int e = isW ? i - NA : i;
        int lane = e & 63;
        int fr = lane & 15, fk = lane >> 4;
        int kt = isW ? ((e >> 8) & 63) : ((e >> 9) & 63);
        int k  = kt * 32 + fk * 8;
        int row;
        if (isW) {
            int g  = (e >> 6) & 3;
            int wn = (e >> 14) & 3;
            int hqq = e >> 16;
            row = g * 1024 + hqq * 64 + wn * 16 + fr;
        } else {
            int m  = (e >> 6) & 7;
            int wmm = (e >> 15) & 1;
            int mii = e >> 16;
            row = mii * 256 + wmm * 128 + m * 16 + fr;
        }
        const float* s0 = isW ? wih : input;
        const float* s1 = isW ? whh : hx;
        const float* src = (k < 1024) ? (s0 + (size_t)row * 1024 + k)
                                      : (s1 + (size_t)row * 1024 + (k - 1024));
        float4 v0 = *(const float4*)src;
        float4 v1 = *(const float4*)(src + 4);
        u16* dst = (isW ? Wp : Ap) + (size_t)e * 8;
        *(ushort4*)dst = make_ushort4(f2h_bits(v0.x), f2h_bits(v0.y),
                                      f2h_bits(v0.z), f2h_bits(v0.w));
        *(ushort4*)(dst + 4) = make_ushort4(f2h_bits(v1.x), f2h_bits(v1.y),
                                            f2h_bits(v1.z), f2h_bits(v1.w));
    }
}

// ---------------- fused GEMM + LSTM epilogue (no LDS, no barriers) ----------------
__device__ __forceinline__ float sigmf(float x) { return 1.0f / (1.0f + __expf(-x)); }
__device__ __forceinline__ float tanhfast(float x) { return 1.0f - 2.0f / (1.0f + __expf(2.0f * x)); }

__launch_bounds__(512, 1)
__global__ void lstm_fused(const u16* __restrict__ Ap, const u16* __restrict__ Wp,
                           const float* __restrict__ cx, const float* __restrict__ eps_c,
                           const float* __restrict__ eps_h,
                           const float* __restrict__ bias_ih, const float* __restrict__ bias_hh,
                           const float* __restrict__ noise_q, const float* __restrict__ noise_e,
                           float* __restrict__ out)
{
    int bid = blockIdx.x;
    // XCD-bijective swizzle: XCD x gets w in [32x,32x+32) -> 2 hq values
    // (W slice 2 MB packed, L2-resident) x all 16 A panels (L3-resident).
    int w = (bid & 7) * 32 + (bid >> 3);
    int mi = w & 15;          // 16 M-chunks of 256 rows
    int hq = w >> 4;          // 16 h-chunks of 64 cols (x4 gates)
    int bm0 = mi * BM;
    int h0 = hq * 64;

    int tid  = threadIdx.x;
    int lane = tid & 63;
    int wid  = tid >> 6;      // 0..7
    int wm   = wid >> 2;      // M half (128 rows)
    int wn   = wid & 3;       // h quarter (16 cols x 4 gates)
    int fr   = lane & 15, fk = lane >> 4;

    // fragment base pointers (u16 units); bumped per step (imm-offset loads)
    const u16* pAt = Ap + ((size_t)(mi * 2 + wm)) * (64 * 8 * 64 * 8) + lane * 8;
    const u16* pWt = Wp + ((size_t)(hq * 4 + wn)) * (64 * 4 * 64 * 8) + lane * 8;

#define LD8(p) __builtin_bit_cast(half8, *(const short8*)(p))

    // loads from bumped bases with compile-time offsets
#define LOADF_P(AA, WW, ofsA, ofsW) do { \
        _Pragma("unroll") \
        for (int m = 0; m < 8; ++m) AA[m] = LD8(pAt + (ofsA) + m * 512); \
        _Pragma("unroll") \
        for (int g = 0; g < 4; ++g) WW[g] = LD8(pWt + (ofsW) + g * 512); \
    } while (0)

#define DOMFMA(AA, WW) do { \
        __builtin_amdgcn_s_setprio(1); \
        _Pragma("unroll") \
        for (int g = 0; g < 4; ++g) \
            _Pragma("unroll") \
            for (int m = 0; m < 8; ++m) \
                acc[m][g] = __builtin_amdgcn_mfma_f32_16x16x32_f16(AA[m], WW[g], acc[m][g], 0, 0, 0); \
        __builtin_amdgcn_s_setprio(0); \
    } while (0)

    f32x4 acc[8][4];
#pragma unroll
    for (int m = 0; m < 8; ++m)
#pragma unroll
        for (int g = 0; g < 4; ++g)
            acc[m][g] = (f32x4){0.f, 0.f, 0.f, 0.f};

    half8 aX[8], wX[4], aY[8], wY[4];
    LOADF_P(aX, wX, 0, 0);

#pragma unroll 1
    for (int t = 0; t < T_STEPS; t += 2) {
        LOADF_P(aY, wY, 4096, 2048);   // prefetch odd step into Y
        DOMFMA(aX, wX);                // compute even step (waits only on X)
        if (t + 2 < T_STEPS) LOADF_P(aX, wX, 8192, 4096);   // next even into X
        DOMFMA(aY, wY);                // compute odd step
        pAt += 8192;                   // advance 2 K-steps
        pWt += 4096;
    }

    // ---- epilogue: batch-load ALL cx/eps first (operand regs are dead), then compute ----
    float sq_e = sqrtf(noise_e[0]);
    float sq_q = sqrtf(noise_q[0]);
    int h = h0 + wn * 16 + fr;
    float bsum[4];
#pragma unroll
    for (int g = 0; g < 4; ++g)
        bsum[g] = bias_ih[g * 1024 + h] + bias_hh[g * 1024 + h];

    float vcx[8][4], vec_[8][4], veh[8][4];
#pragma unroll
    for (int m = 0; m < 8; ++m) {
        int r0 = bm0 + wm * 128 + m * 16 + fk * 4;
#pragma unroll
        for (int j = 0; j < 4; ++j) {
            size_t off = (size_t)(r0 + j) * HDIM + h;
            vcx[m][j] = cx[off];
            vec_[m][j] = eps_c[off];
            veh[m][j] = eps_h[off];
        }
    }
#pragma unroll
    for (int m = 0; m < 8; ++m) {
        int r0 = bm0 + wm * 128 + m * 16 + fk * 4;
#pragma unroll
        for (int j = 0; j < 4; ++j) {
            size_t off = (size_t)(r0 + j) * HDIM + h;
            float gi = acc[m][0][j] + bsum[0];
            float gf = acc[m][1][j] + bsum[1];
            float gc = acc[m][2][j] + bsum[2];
            float go = acc[m][3][j] + bsum[3];
            float ig = sigmf(gi), fg = sigmf(gf);
            float cg = tanhfast(gc), og = sigmf(go);
            float cyv = fg * vcx[m][j] + ig * cg + sq_e * vec_[m][j];
            float hyv = og * tanhfast(cyv) + sq_q * veh[m][j];
            out[off] = hyv;                                 // hy
            out[(size_t)B_ROWS * HDIM + off] = cyv;         // cy
        }
    }
}

extern "C" void kernel_launch(void* const* d_in, const int* in_sizes, int n_in,
                              void* d_out, int out_size, void* d_ws, size_t ws_size,
                              hipStream_t stream)
{
    const float* input = (const float*)d_in[0];
    const float* hx    = (const float*)d_in[1];
    const float* cx    = (const float*)d_in[2];
    const float* nq    = (const float*)d_in[3];
    const float* ne    = (const float*)d_in[4];
    const float* wih   = (const float*)d_in[5];
    const float* whh   = (const float*)d_in[6];
    const float* bih   = (const float*)d_in[7];
    const float* bhh   = (const float*)d_in[8];
    const float* epsc  = (const float*)d_in[9];
    const float* epsh  = (const float*)d_in[10];
    float* out = (float*)d_out;

    u16* Ap = (u16*)d_ws;
    u16* Wp = Ap + (size_t)B_ROWS * KDIM;   // 32 MB of ws total

    hipLaunchKernelGGL(pack_kernel, dim3(2048), dim3(256), 0, stream,
                       input, hx, wih, whh, Ap, Wp);
    hipLaunchKernelGGL(lstm_fused, dim3(256), dim3(512), 0, stream,
                       Ap, Wp, cx, epsc, epsh, bih, bhh, nq, ne, out);
}